// Round 1
// 296.257 us; speedup vs baseline: 1.1734x; 1.1734x over previous
//
#include <hip/hip_runtime.h>
#include <math.h>

constexpr int Bb = 64, Nn = 512, Vv = 64, Hh = 512, Rr = 4, Aa = 18, INp = 128, KTOP = 32;
constexpr int CIN = 384;   // IN + R*V
constexpr int WOUT = 195;  // 3V+3
#define EPSf 1e-8f

__device__ __forceinline__ float sigmoidf(float x){ return 1.f/(1.f+expf(-x)); }
__device__ __forceinline__ float softplusf(float x){ return (x>20.f)? x : log1pf(expf(x)); }
__device__ __forceinline__ float wave_reduce(float v){
  #pragma unroll
  for(int o=32;o>0;o>>=1) v += __shfl_down(v, o, 64);
  return v;
}
// order-preserving float->uint transform (total order incl. negatives)
__device__ __forceinline__ unsigned f2ord(float f){
  unsigned u = __float_as_uint(f);
  return (u & 0x80000000u) ? ~u : (u | 0x80000000u);
}

// ---- 1. stage1: fwbw (blocks 0..511) + read-proj w/ key-norm epilogue (blocks 512..767) ----
// Also zeroes ws_rvec (blocks 0..63) for the later atomic accumulation.
__global__ void k_stage1(const float* __restrict__ link, const float* __restrict__ rw,
                         const float* __restrict__ Wr, const float* __restrict__ brd,
                         const float* __restrict__ h,
                         float* __restrict__ fw, float* __restrict__ bwpart,
                         float* __restrict__ rvec,
                         float* __restrict__ ro, float* __restrict__ rp) {
  __shared__ float bl[4][4][512];   // fwbw: [wave][r][j]  32 KB
  __shared__ float sh[512];         // read-proj: staged h
  __shared__ float sro[68];         // read-proj: outputs of this (b,r)
  if (blockIdx.x < 512) {
    // ---------------- fwbw ----------------
    if (blockIdx.x < 64) rvec[blockIdx.x*256 + threadIdx.x] = 0.f;
    int b  = blockIdx.x >> 3;
    int ch = blockIdx.x & 7;
    int wv = threadIdx.x >> 6, lane = threadIdx.x & 63;
    const float* rwb = rw + b*Rr*Nn;
    float rwv[4][8];
    #pragma unroll
    for (int r = 0; r < 4; ++r)
      #pragma unroll
      for (int t = 0; t < 8; ++t) rwv[r][t] = rwb[r*512 + lane + 64*t];
    float bwacc[8][4] = {};
    const float* lb = link + (size_t)b*Nn*Nn;
    int n0 = ch*64 + wv*16;
    for (int i = 0; i < 16; ++i) {
      int n = n0 + i;
      float lk[8];
      #pragma unroll
      for (int t = 0; t < 8; ++t) lk[t] = lb[n*512 + lane + 64*t];
      float s0 = rwb[n], s1 = rwb[512+n], s2 = rwb[1024+n], s3 = rwb[1536+n];
      float f0=0,f1=0,f2=0,f3=0;
      #pragma unroll
      for (int t = 0; t < 8; ++t) {
        float lv = lk[t];
        f0 += lv*rwv[0][t]; f1 += lv*rwv[1][t]; f2 += lv*rwv[2][t]; f3 += lv*rwv[3][t];
        bwacc[t][0] += lv*s0; bwacc[t][1] += lv*s1; bwacc[t][2] += lv*s2; bwacc[t][3] += lv*s3;
      }
      f0 = wave_reduce(f0); f1 = wave_reduce(f1);
      f2 = wave_reduce(f2); f3 = wave_reduce(f3);
      if (lane == 0) {
        fw[(b*Rr+0)*Nn+n] = f0; fw[(b*Rr+1)*Nn+n] = f1;
        fw[(b*Rr+2)*Nn+n] = f2; fw[(b*Rr+3)*Nn+n] = f3;
      }
    }
    #pragma unroll
    for (int t = 0; t < 8; ++t)
      #pragma unroll
      for (int r = 0; r < 4; ++r) bl[wv][r][lane + 64*t] = bwacc[t][r];
    __syncthreads();
    int tid = threadIdx.x;
    #pragma unroll
    for (int q = 0; q < 8; ++q) {
      int idx = q*256 + tid;        // r*512 + j
      int r = idx >> 9, j = idx & 511;
      float v = bl[0][r][j] + bl[1][r][j] + bl[2][r][j] + bl[3][r][j];
      bwpart[((size_t)(ch*Bb + b)*Rr + r)*Nn + j] = v;
    }
  } else {
    // ---------------- read projection, block per (b,r) ----------------
    int blk = blockIdx.x - 512;
    int b = blk >> 2, r = blk & 3;
    int wv = threadIdx.x >> 6, lane = threadIdx.x & 63;
    const float* hb = h + b*Hh;
    for (int i = threadIdx.x; i < 512; i += 256) sh[i] = hb[i];
    __syncthreads();
    const float* wbase = Wr + (size_t)(r*68)*Hh;
    for (int q = 0; q < 17; ++q) {
      int p = wv*17 + q;
      const float* wrow = wbase + (size_t)p*Hh;
      float acc = 0.f;
      #pragma unroll
      for (int t = 0; t < 8; ++t) { int k = lane + 64*t; acc += wrow[k]*sh[k]; }
      acc = wave_reduce(acc);
      if (lane == 0) sro[p] = acc + brd[r*68 + p];
    }
    __syncthreads();
    if (threadIdx.x < 68) ro[b*272 + r*68 + threadIdx.x] = sro[threadIdx.x];
    if (wv == 0) {
      float kv = sro[lane];            // keys are sro[0..63]
      float k2 = wave_reduce(kv*kv);
      if (lane == 0) {
        float rbeta = softplusf(sro[64]);
        float sc = rbeta / fmaxf(sqrtf(k2), EPSf);   // rbeta * inv_keynorm
        float e0 = sro[65], e1 = sro[66], e2 = sro[67];
        float mm = fmaxf(e0, fmaxf(e1, e2));
        float x0 = expf(e0-mm), x1 = expf(e1-mm), x2 = expf(e2-mm);
        float inv = 1.f/(x0+x1+x2);
        float* rpb = rp + (b*4 + r)*4;
        rpb[0] = sc; rpb[1] = x0*inv; rpb[2] = x1*inv; rpb[3] = x2*inv;
      }
    }
  }
}

// ---- 2. scores: one interleaved 5-value reduce per row; stores inv mem-norm ----
__global__ void k_scores(const float* __restrict__ mem, const float* __restrict__ ro,
                         const float* __restrict__ rp, float* __restrict__ scores,
                         float* __restrict__ invmn) {
  int row = blockIdx.x*4 + (threadIdx.x>>6);
  int lane = threadIdx.x & 63;
  int b = row >> 9, n = row & 511;
  float m = mem[row*Vv + lane];
  const float* rob = ro + b*272;
  float v0 = m*m;
  float v1 = m * rob[lane];
  float v2 = m * rob[68  + lane];
  float v3 = m * rob[136 + lane];
  float v4 = m * rob[204 + lane];
  #pragma unroll
  for (int o = 32; o > 0; o >>= 1) {
    v0 += __shfl_down(v0,o,64); v1 += __shfl_down(v1,o,64);
    v2 += __shfl_down(v2,o,64); v3 += __shfl_down(v3,o,64);
    v4 += __shfl_down(v4,o,64);
  }
  if (lane == 0) {
    float im = 1.f / fmaxf(sqrtf(v0), EPSf);
    invmn[row] = im;
    const float* rpb = rp + b*16;
    scores[(b*4+0)*Nn+n] = rpb[0]  * v1 * im;
    scores[(b*4+1)*Nn+n] = rpb[4]  * v2 * im;
    scores[(b*4+2)*Nn+n] = rpb[8]  * v3 * im;
    scores[(b*4+3)*Nn+n] = rpb[12] * v4 * im;
  }
}

// ---- 3. kth-largest via barrier-free all-pairs rank + masked softmax ----
__global__ void k_topk_cw(const float* __restrict__ scores, float* __restrict__ cw) {
  __shared__ unsigned long long sk[512];
  __shared__ float sred[4];
  __shared__ float skv[2];   // [0]=kth, [1]=max
  int br = blockIdx.x, tid = threadIdx.x;
  float v0 = scores[br*Nn + tid], v1 = scores[br*Nn + tid + 256];
  // unique keys: desc value, asc index tiebreak  (matches top_k semantics)
  unsigned long long k0 = ((unsigned long long)f2ord(v0) << 32) | (unsigned)(511 - tid);
  unsigned long long k1 = ((unsigned long long)f2ord(v1) << 32) | (unsigned)(255 - tid);
  sk[tid] = k0; sk[tid+256] = k1;
  __syncthreads();
  int c0 = 0, c1 = 0;
  #pragma unroll 8
  for (int j = 0; j < 512; ++j) {
    unsigned long long kj = sk[j];
    c0 += (kj > k0); c1 += (kj > k1);
  }
  if (c0 == KTOP-1) skv[0] = v0;
  if (c1 == KTOP-1) skv[0] = v1;
  if (c0 == 0) skv[1] = v0;
  if (c1 == 0) skv[1] = v1;
  __syncthreads();
  float kth = skv[0], mx = skv[1];
  float e0 = (v0 >= kth) ? expf(v0-mx) : 0.f;
  float e1 = (v1 >= kth) ? expf(v1-mx) : 0.f;
  float s = wave_reduce(e0+e1);
  if ((tid&63) == 0) sred[tid>>6] = s;
  __syncthreads();
  float inv = 1.f/(sred[0]+sred[1]+sred[2]+sred[3]);
  cw[br*Nn+tid]     = e0*inv;
  cw[br*Nn+tid+256] = e1*inv;
}

// ---- 4. fused w_r + psi + usage_new + rvec partial (block per (b, 256-chunk)) ----
__global__ void k_wrrv(const float* __restrict__ bwpart, const float* __restrict__ cw,
                       const float* __restrict__ fw, const float* __restrict__ rp,
                       const float* __restrict__ usage, const float* __restrict__ wwt,
                       const float* __restrict__ mem,
                       float* __restrict__ out_wr, float* __restrict__ out_usage,
                       float* __restrict__ rvec) {
  __shared__ float swr[4][256];
  int b = blockIdx.x >> 1, ch = blockIdx.x & 1;
  int tid = threadIdx.x;
  int n = ch*256 + tid;
  int idx = b*Nn + n;
  float psi = 1.f;
  #pragma unroll
  for (int r = 0; r < 4; ++r) {
    int brr = b*4 + r;
    float bwv = 0.f;
    #pragma unroll
    for (int chh = 0; chh < 8; ++chh)
      bwv += bwpart[((size_t)(chh*Bb + b)*Rr + r)*Nn + n];
    const float* rpb = rp + brr*4;
    float w = rpb[1]*bwv + rpb[2]*cw[brr*Nn+n] + rpb[3]*fw[brr*Nn+n];
    out_wr[brr*Nn+n] = w;
    swr[r][tid] = w;
    psi *= (1.f - w);
  }
  float u = usage[idx], wt = wwt[idx];
  out_usage[idx] = (u + wt - u*wt) * psi;
  __syncthreads();
  int r = tid >> 6, v = tid & 63;
  const float* mb = mem + ((size_t)b*Nn + ch*256)*Vv + v;
  float acc = 0.f;
  #pragma unroll 4
  for (int t = 0; t < 256; ++t) acc += swr[r][t] * mb[t*Vv];
  atomicAdd(&rvec[(b*4+r)*Vv + v], acc);
}

// ---- 5. gates GEMM fused with LSTM: wave computes 4 gates of one h x 4 b ----
__global__ void k_gates_lstm(const float* __restrict__ x, const float* __restrict__ rvec,
                             const float* __restrict__ h, const float* __restrict__ Wih,
                             const float* __restrict__ Whh, const float* __restrict__ bih,
                             const float* __restrict__ bhh, const float* __restrict__ c,
                             float* __restrict__ out_h, float* __restrict__ out_c) {
  int gid = blockIdx.x*4 + (threadIdx.x>>6);   // hh*16 + bt
  int lane = threadIdx.x & 63;
  int hh = gid >> 4;    // 0..511
  int bt = gid & 15;    // 0..15
  float acc[4][4] = {};
  #pragma unroll
  for (int t = 0; t < 6; ++t) {
    int k = lane + 64*t;
    float u[4], w[4];
    #pragma unroll
    for (int i = 0; i < 4; ++i) {
      int b = bt*4 + i;
      u[i] = (k < INp) ? x[b*INp + k] : rvec[b*(Rr*Vv) + k - INp];
      w[i] = Wih[(size_t)(i*Hh + hh)*CIN + k];     // i = gate index
    }
    #pragma unroll
    for (int g = 0; g < 4; ++g)
      #pragma unroll
      for (int bb = 0; bb < 4; ++bb) acc[g][bb] += w[g]*u[bb];
  }
  #pragma unroll
  for (int t = 0; t < 8; ++t) {
    int k = lane + 64*t;
    float u[4], w[4];
    #pragma unroll
    for (int i = 0; i < 4; ++i) {
      u[i] = h[(bt*4+i)*Hh + k];
      w[i] = Whh[(size_t)(i*Hh + hh)*Hh + k];
    }
    #pragma unroll
    for (int g = 0; g < 4; ++g)
      #pragma unroll
      for (int bb = 0; bb < 4; ++bb) acc[g][bb] += w[g]*u[bb];
  }
  #pragma unroll
  for (int g = 0; g < 4; ++g)
    #pragma unroll
    for (int bb = 0; bb < 4; ++bb) acc[g][bb] = wave_reduce(acc[g][bb]);
  if (lane == 0) {
    float bsum[4];
    #pragma unroll
    for (int g = 0; g < 4; ++g) bsum[g] = bih[g*Hh + hh] + bhh[g*Hh + hh];
    #pragma unroll
    for (int bb = 0; bb < 4; ++bb) {
      int b = bt*4 + bb;
      float ig = sigmoidf(acc[0][bb] + bsum[0]);
      float fg = sigmoidf(acc[1][bb] + bsum[1]);
      float gg = tanhf   (acc[2][bb] + bsum[2]);
      float og = sigmoidf(acc[3][bb] + bsum[3]);
      float cn = fg * c[b*Hh + hh] + ig * gg;
      float hn = og * tanhf(cn);
      out_c[b*Hh + hh] = cn;
      out_h[b*Hh + hh] = hn;
    }
  }
}

// ---- 6. wo + policy + value ; wave per (b,o), o in [0,214) ----
__global__ void k_wopol(const float* __restrict__ hn, const float* __restrict__ Ww,
                        const float* __restrict__ bw_, const float* __restrict__ Wp,
                        const float* __restrict__ bp, const float* __restrict__ Wv,
                        const float* __restrict__ bv, float* __restrict__ wo,
                        float* __restrict__ out_logits, float* __restrict__ out_value) {
  int gid = blockIdx.x*4 + (threadIdx.x>>6);
  int lane = threadIdx.x & 63;
  int b = gid / 214, o = gid % 214;
  const float* wrow;
  if (o < WOUT) wrow = Ww + o*Hh;
  else if (o < WOUT + Aa) wrow = Wp + (o-WOUT)*Hh;
  else wrow = Wv;
  const float* hb = hn + b*Hh;
  float acc = 0.f;
  #pragma unroll
  for (int t = 0; t < 8; ++t) { int k = lane+64*t; acc += hb[k]*wrow[k]; }
  acc = wave_reduce(acc);
  if (lane == 0) {
    if (o < WOUT) wo[b*WOUT+o] = acc + bw_[o];
    else if (o < WOUT + Aa) out_logits[b*Aa + (o-WOUT)] = acc + bp[o-WOUT];
    else out_value[b] = acc + bv[0];
  }
}

// ---- 7. wsim: interleaved 2-value reduce, mem-norm from k_scores ----
__global__ void k_wsim(const float* __restrict__ mem, const float* __restrict__ wo,
                       const float* __restrict__ invmn, float* __restrict__ wsim) {
  int row = blockIdx.x*4 + (threadIdx.x>>6);
  int lane = threadIdx.x & 63;
  int b = row >> 9;
  const float* wob = wo + b*WOUT;
  float kv = wob[lane];
  float m = mem[row*Vv + lane];
  float v0 = m*kv, v1 = kv*kv;
  #pragma unroll
  for (int o = 32; o > 0; o >>= 1) {
    v0 += __shfl_down(v0,o,64); v1 += __shfl_down(v1,o,64);
  }
  if (lane == 0) {
    float wbeta = softplusf(wob[192]);
    wsim[row] = wbeta * v0 * invmn[row] / fmaxf(sqrtf(v1), EPSf);
  }
}

// ---- 8. softmax(wsim) + rank-based allocation + write_w + prec_new ; block per b ----
__global__ void k_alloc(const float* __restrict__ usage, const float* __restrict__ wo,
                        const float* __restrict__ wsim, const float* __restrict__ prec,
                        float* __restrict__ out_ww, float* __restrict__ out_prec) {
  __shared__ unsigned long long sk[512];
  __shared__ float su[512];
  __shared__ float cp[512];
  __shared__ float sred[8];
  int b = blockIdx.x, tid = threadIdx.x;
  int wv = tid >> 6, lane = tid & 63;
  float s0 = wsim[b*Nn+tid], s1 = wsim[b*Nn+tid+256];
  float u0 = usage[b*Nn+tid], u1 = usage[b*Nn+tid+256];
  // unique keys: asc value, asc index tiebreak (= stable argsort)
  unsigned long long k0 = ((unsigned long long)f2ord(u0) << 32) | (unsigned)tid;
  unsigned long long k1 = ((unsigned long long)f2ord(u1) << 32) | (unsigned)(tid+256);
  sk[tid] = k0; sk[tid+256] = k1;
  float mxl = fmaxf(s0, s1);
  #pragma unroll
  for (int o = 32; o > 0; o >>= 1) mxl = fmaxf(mxl, __shfl_down(mxl,o,64));
  if (lane == 0) sred[wv] = mxl;
  __syncthreads();
  float mx = fmaxf(fmaxf(sred[0],sred[1]), fmaxf(sred[2],sred[3]));
  float e0 = expf(s0-mx), e1 = expf(s1-mx);
  float ssum = wave_reduce(e0+e1);
  if (lane == 0) sred[4+wv] = ssum;
  // rank loop overlaps the sum barrier
  int r0 = 0, r1 = 0;
  #pragma unroll 8
  for (int j = 0; j < 512; ++j) {
    unsigned long long kj = sk[j];
    r0 += (kj < k0); r1 += (kj < k1);
  }
  __syncthreads();
  float cinv = 1.f/(sred[4]+sred[5]+sred[6]+sred[7]);
  float c0 = e0*cinv, c1 = e1*cinv;
  su[r0] = u0; su[r1] = u1;       // scatter into sorted order (ranks are a permutation)
  __syncthreads();
  cp[tid] = su[tid]; cp[tid+256] = su[tid+256];
  __syncthreads();
  for (int d = 1; d < 512; d <<= 1) {
    float t0 = cp[tid]     * ((tid >= d)     ? cp[tid-d]     : 1.f);
    float t1 = cp[tid+256] * ((tid+256 >= d) ? cp[tid+256-d] : 1.f);
    __syncthreads();
    cp[tid] = t0; cp[tid+256] = t1;
    __syncthreads();
  }
  float pp0 = (r0 == 0) ? 1.f : cp[r0-1];
  float pp1 = (r1 == 0) ? 1.f : cp[r1-1];
  float a0 = (1.f-u0)*pp0, a1 = (1.f-u1)*pp1;
  float ga = sigmoidf(wo[b*WOUT+193]);
  float gw = sigmoidf(wo[b*WOUT+194]);
  float wv0 = gw * (ga*a0 + (1.f-ga)*c0);
  float wv1 = gw * (ga*a1 + (1.f-ga)*c1);
  out_ww[b*Nn+tid]     = wv0;
  out_ww[b*Nn+tid+256] = wv1;
  float ws_ = wave_reduce(wv0+wv1);
  if (lane == 0) sred[wv] = ws_;
  __syncthreads();
  float wsum = sred[0]+sred[1]+sred[2]+sred[3];
  out_prec[b*Nn+tid]     = (1.f-wsum)*prec[b*Nn+tid]     + wv0;
  out_prec[b*Nn+tid+256] = (1.f-wsum)*prec[b*Nn+tid+256] + wv1;
}

// ---- 9. fused link_new + mem_new elementwise, float4 ----
__global__ void k_memlink(const float* __restrict__ link, const float* __restrict__ ww,
                          const float* __restrict__ prec, const float* __restrict__ mem,
                          const float* __restrict__ wo, float* __restrict__ out_link,
                          float* __restrict__ out_mem) {
  int bid = blockIdx.x;
  if (bid < 16384) {
    int idx4 = bid*256 + threadIdx.x;
    int base = idx4*4;
    int b = base >> 18;
    int rem = base & 262143;
    int i = rem >> 9;
    int j0 = rem & 511;
    float wi = ww[b*Nn + i];
    float fi = 1.f - wi;
    float4 lv = *(const float4*)(link + base);
    float4 wj = *(const float4*)(ww + b*Nn + j0);
    float4 pj = *(const float4*)(prec + b*Nn + j0);
    float4 o;
    o.x = fi*(1.f-wj.x)*lv.x + wi*pj.x;
    o.y = fi*(1.f-wj.y)*lv.y + wi*pj.y;
    o.z = fi*(1.f-wj.z)*lv.z + wi*pj.z;
    o.w = fi*(1.f-wj.w)*lv.w + wi*pj.w;
    if (i >= j0 && i < j0+4) {
      if (i == j0) o.x = 0.f;
      else if (i == j0+1) o.y = 0.f;
      else if (i == j0+2) o.z = 0.f;
      else o.w = 0.f;
    }
    *(float4*)(out_link + base) = o;
  } else {
    int idx4 = (bid - 16384)*256 + threadIdx.x;
    int base = idx4*4;
    int b = base >> 15;
    int rem = base & 32767;
    int n = rem >> 6;
    int v0 = rem & 63;
    float w = ww[b*Nn + n];
    const float* wob = wo + b*WOUT;
    float4 m = *(const float4*)(mem + base);
    float4 o;
    float e, a;
    e = sigmoidf(wob[64+v0+0]); a = tanhf(wob[128+v0+0]); o.x = m.x*(1.f-w*e)+w*a;
    e = sigmoidf(wob[64+v0+1]); a = tanhf(wob[128+v0+1]); o.y = m.y*(1.f-w*e)+w*a;
    e = sigmoidf(wob[64+v0+2]); a = tanhf(wob[128+v0+2]); o.z = m.z*(1.f-w*e)+w*a;
    e = sigmoidf(wob[64+v0+3]); a = tanhf(wob[128+v0+3]); o.w = m.w*(1.f-w*e)+w*a;
    *(float4*)(out_mem + base) = o;
  }
}

extern "C" void kernel_launch(void* const* d_in, const int* in_sizes, int n_in,
                              void* d_out, int out_size, void* d_ws, size_t ws_size,
                              hipStream_t stream) {
  const float* x    = (const float*)d_in[0];
  const float* h    = (const float*)d_in[1];
  const float* c    = (const float*)d_in[2];
  const float* mem  = (const float*)d_in[3];
  const float* rw   = (const float*)d_in[4];
  const float* wwt  = (const float*)d_in[5];
  const float* usage= (const float*)d_in[6];
  const float* link = (const float*)d_in[7];
  const float* prec = (const float*)d_in[8];
  const float* Wih  = (const float*)d_in[9];
  const float* Whh  = (const float*)d_in[10];
  const float* bih  = (const float*)d_in[11];
  const float* bhh  = (const float*)d_in[12];
  const float* Wr   = (const float*)d_in[13];
  const float* br   = (const float*)d_in[14];
  const float* Ww   = (const float*)d_in[15];
  const float* bw_  = (const float*)d_in[16];
  const float* Wp   = (const float*)d_in[17];
  const float* bp   = (const float*)d_in[18];
  const float* Wv   = (const float*)d_in[19];
  const float* bv   = (const float*)d_in[20];

  float* out = (float*)d_out;
  float* o_logits = out + 0;
  float* o_value  = out + 1152;
  float* o_h      = out + 1216;
  float* o_c      = out + 33984;
  float* o_mem    = out + 66752;
  float* o_wr     = out + 2163904;
  float* o_ww     = out + 2294976;
  float* o_usage  = out + 2327744;
  float* o_link   = out + 2360512;
  float* o_prec   = out + 19137728;

  float* ws = (float*)d_ws;
  float* ws_ro     = ws;              // 17408
  float* ws_rp     = ws + 17408;      // 1024  (b,r): {rbeta/knorm, pi0, pi1, pi2}
  float* ws_sc     = ws + 18432;      // 131072
  float* ws_cw     = ws + 149504;     // 131072
  float* ws_fw     = ws + 280576;     // 131072
  float* ws_bwpart = ws + 411648;     // 1048576
  float* ws_rvec   = ws + 1460224;    // 16384 (zeroed in k_stage1, atomic acc)
  float* ws_wo     = ws + 1476608;    // 12480
  float* ws_wsim   = ws + 1489088;    // 32768
  float* ws_invmn  = ws + 1521856;    // 32768  (end ~6.2 MB)

  k_stage1     <<<dim3(768),       dim3(256), 0, stream>>>(link, rw, Wr, br, h, ws_fw, ws_bwpart, ws_rvec, ws_ro, ws_rp);
  k_scores     <<<dim3(Bb*Nn/4),   dim3(256), 0, stream>>>(mem, ws_ro, ws_rp, ws_sc, ws_invmn);
  k_topk_cw    <<<dim3(Bb*Rr),     dim3(256), 0, stream>>>(ws_sc, ws_cw);
  k_wrrv       <<<dim3(Bb*2),      dim3(256), 0, stream>>>(ws_bwpart, ws_cw, ws_fw, ws_rp, usage, wwt, mem, o_wr, o_usage, ws_rvec);
  k_gates_lstm <<<dim3(2048),      dim3(256), 0, stream>>>(x, ws_rvec, h, Wih, Whh, bih, bhh, c, o_h, o_c);
  k_wopol      <<<dim3(Bb*214/4),  dim3(256), 0, stream>>>(o_h, Ww, bw_, Wp, bp, Wv, bv, ws_wo, o_logits, o_value);
  k_wsim       <<<dim3(Bb*Nn/4),   dim3(256), 0, stream>>>(mem, ws_wo, ws_invmn, ws_wsim);
  k_alloc      <<<dim3(Bb),        dim3(256), 0, stream>>>(usage, ws_wo, ws_wsim, prec, o_ww, o_prec);
  k_memlink    <<<dim3(16384+2048),dim3(256), 0, stream>>>(link, o_ww, prec, mem, ws_wo, o_link, o_mem);
}

// Round 2
// 285.446 us; speedup vs baseline: 1.2178x; 1.0379x over previous
//
#include <hip/hip_runtime.h>
#include <math.h>

constexpr int Bb = 64, Nn = 512, Vv = 64, Hh = 512, Rr = 4, Aa = 18, INp = 128, KTOP = 32;
constexpr int CIN = 384;   // IN + R*V
constexpr int WOUT = 195;  // 3V+3
#define EPSf 1e-8f

__device__ __forceinline__ float sigmoidf(float x){ return 1.f/(1.f+expf(-x)); }
__device__ __forceinline__ float softplusf(float x){ return (x>20.f)? x : log1pf(expf(x)); }
__device__ __forceinline__ float wave_reduce(float v){
  #pragma unroll
  for(int o=32;o>0;o>>=1) v += __shfl_down(v, o, 64);
  return v;
}
// order-preserving float->uint transform (total order incl. negatives)
__device__ __forceinline__ unsigned f2ord(float f){
  unsigned u = __float_as_uint(f);
  return (u & 0x80000000u) ? ~u : (u | 0x80000000u);
}

// ---- K1: blocks 0..511 = fwbw (+rvec zero) ; blocks 512..767 = per-(b,r)
//          read-proj + scores + exact-kth topk + masked softmax (cw), all in LDS ----
__global__ void k_stage1(const float* __restrict__ link, const float* __restrict__ rw,
                         const float* __restrict__ Wr, const float* __restrict__ brd,
                         const float* __restrict__ h, const float* __restrict__ mem,
                         float* __restrict__ fw, float* __restrict__ bwpart,
                         float* __restrict__ rvec, float* __restrict__ rp,
                         float* __restrict__ cw) {
  __shared__ __align__(16) float smem[8192];   // 32 KB union
  if (blockIdx.x < 512) {
    // ---------------- fwbw ----------------
    float (*bl)[4][512] = reinterpret_cast<float (*)[4][512]>(smem);  // [wave][r][j]
    if (blockIdx.x < 64) rvec[blockIdx.x*256 + threadIdx.x] = 0.f;
    int b  = blockIdx.x >> 3;
    int ch = blockIdx.x & 7;
    int wv = threadIdx.x >> 6, lane = threadIdx.x & 63;
    const float* rwb = rw + b*Rr*Nn;
    float rwv[4][8];
    #pragma unroll
    for (int r = 0; r < 4; ++r)
      #pragma unroll
      for (int t = 0; t < 8; ++t) rwv[r][t] = rwb[r*512 + lane + 64*t];
    float bwacc[8][4] = {};
    const float* lb = link + (size_t)b*Nn*Nn;
    int n0 = ch*64 + wv*16;
    for (int i = 0; i < 16; ++i) {
      int n = n0 + i;
      float lk[8];
      #pragma unroll
      for (int t = 0; t < 8; ++t) lk[t] = lb[n*512 + lane + 64*t];
      float s0 = rwb[n], s1 = rwb[512+n], s2 = rwb[1024+n], s3 = rwb[1536+n];
      float f0=0,f1=0,f2=0,f3=0;
      #pragma unroll
      for (int t = 0; t < 8; ++t) {
        float lv = lk[t];
        f0 += lv*rwv[0][t]; f1 += lv*rwv[1][t]; f2 += lv*rwv[2][t]; f3 += lv*rwv[3][t];
        bwacc[t][0] += lv*s0; bwacc[t][1] += lv*s1; bwacc[t][2] += lv*s2; bwacc[t][3] += lv*s3;
      }
      f0 = wave_reduce(f0); f1 = wave_reduce(f1);
      f2 = wave_reduce(f2); f3 = wave_reduce(f3);
      if (lane == 0) {
        fw[(b*Rr+0)*Nn+n] = f0; fw[(b*Rr+1)*Nn+n] = f1;
        fw[(b*Rr+2)*Nn+n] = f2; fw[(b*Rr+3)*Nn+n] = f3;
      }
    }
    #pragma unroll
    for (int t = 0; t < 8; ++t)
      #pragma unroll
      for (int r = 0; r < 4; ++r) bl[wv][r][lane + 64*t] = bwacc[t][r];
    __syncthreads();
    int tid = threadIdx.x;
    #pragma unroll
    for (int q = 0; q < 8; ++q) {
      int idx = q*256 + tid;        // r*512 + j
      int r = idx >> 9, j = idx & 511;
      float v = bl[0][r][j] + bl[1][r][j] + bl[2][r][j] + bl[3][r][j];
      bwpart[((size_t)(ch*Bb + b)*Rr + r)*Nn + j] = v;
    }
  } else {
    // ---------------- read-proj + scores + topk + cw, block per (b,r) ----------------
    float* sh  = smem;                 // 512: staged h
    float* sro = smem + 512;           // 80: ro outputs 0..67, [68]=sc
    unsigned long long* sk = (unsigned long long*)(smem + 592);  // 512 ull (4 KB)
    float* sred = smem + 1616;         // 4
    float* skv  = smem + 1620;         // 2: [0]=kth, [1]=max
    int blk = blockIdx.x - 512;
    int b = blk >> 2, r = blk & 3;
    int tid = threadIdx.x;
    int wv = tid >> 6, lane = tid & 63;
    const float* hb = h + b*Hh;
    for (int i = tid; i < 512; i += 256) sh[i] = hb[i];
    __syncthreads();
    // phase A: 68 dots, 4-way interleaved per wave (17 dots each)
    const float* wbase = Wr + (size_t)(r*68)*Hh;
    int pbase = wv*17;
    #pragma unroll
    for (int g = 0; g < 4; ++g) {
      int p = pbase + g*4;
      const float *w0 = wbase + (size_t)p*Hh, *w1 = w0 + Hh, *w2 = w1 + Hh, *w3 = w2 + Hh;
      float a0=0,a1=0,a2=0,a3=0;
      #pragma unroll
      for (int t = 0; t < 8; ++t) {
        int k = lane + 64*t; float hv = sh[k];
        a0 += w0[k]*hv; a1 += w1[k]*hv; a2 += w2[k]*hv; a3 += w3[k]*hv;
      }
      #pragma unroll
      for (int o = 32; o > 0; o >>= 1) {
        a0 += __shfl_down(a0,o,64); a1 += __shfl_down(a1,o,64);
        a2 += __shfl_down(a2,o,64); a3 += __shfl_down(a3,o,64);
      }
      if (lane == 0) {
        sro[p]   = a0 + brd[r*68+p];   sro[p+1] = a1 + brd[r*68+p+1];
        sro[p+2] = a2 + brd[r*68+p+2]; sro[p+3] = a3 + brd[r*68+p+3];
      }
    }
    {
      int p = pbase + 16;
      const float* w0 = wbase + (size_t)p*Hh;
      float a0 = 0.f;
      #pragma unroll
      for (int t = 0; t < 8; ++t) { int k = lane + 64*t; a0 += w0[k]*sh[k]; }
      a0 = wave_reduce(a0);
      if (lane == 0) sro[p] = a0 + brd[r*68+p];
    }
    __syncthreads();
    if (wv == 0) {
      float kv = sro[lane];
      float k2 = wave_reduce(kv*kv);
      if (lane == 0) {
        float rbeta = softplusf(sro[64]);
        float sc = rbeta / fmaxf(sqrtf(k2), EPSf);    // rbeta * inv_keynorm
        float e0 = sro[65], e1 = sro[66], e2 = sro[67];
        float mm = fmaxf(e0, fmaxf(e1, e2));
        float x0 = expf(e0-mm), x1 = expf(e1-mm), x2 = expf(e2-mm);
        float inv = 1.f/(x0+x1+x2);
        float* rpb = rp + (b*4 + r)*4;
        rpb[0] = sc; rpb[1] = x0*inv; rpb[2] = x1*inv; rpb[3] = x2*inv;
        sro[68] = sc;
      }
    }
    __syncthreads();
    // phase B: scores, thread-per-row x2 (float4 dots, norm inline)
    float sc = sro[68];
    const float4* key4 = (const float4*)sro;
    float v0, v1;
    {
      const float4* m4 = (const float4*)(mem + ((size_t)(b*Nn + tid))*Vv);
      float dot=0.f, nrm=0.f;
      #pragma unroll
      for (int i = 0; i < 16; ++i) {
        float4 mv = m4[i]; float4 kk = key4[i];
        dot += mv.x*kk.x + mv.y*kk.y + mv.z*kk.z + mv.w*kk.w;
        nrm += mv.x*mv.x + mv.y*mv.y + mv.z*mv.z + mv.w*mv.w;
      }
      v0 = sc * dot / fmaxf(sqrtf(nrm), EPSf);
    }
    {
      const float4* m4 = (const float4*)(mem + ((size_t)(b*Nn + tid + 256))*Vv);
      float dot=0.f, nrm=0.f;
      #pragma unroll
      for (int i = 0; i < 16; ++i) {
        float4 mv = m4[i]; float4 kk = key4[i];
        dot += mv.x*kk.x + mv.y*kk.y + mv.z*kk.z + mv.w*kk.w;
        nrm += mv.x*mv.x + mv.y*mv.y + mv.z*mv.z + mv.w*mv.w;
      }
      v1 = sc * dot / fmaxf(sqrtf(nrm), EPSf);
    }
    // phase C: exact kth via all-pairs rank + masked softmax
    unsigned long long k0 = ((unsigned long long)f2ord(v0) << 32) | (unsigned)(511 - tid);
    unsigned long long k1 = ((unsigned long long)f2ord(v1) << 32) | (unsigned)(255 - tid);
    sk[tid] = k0; sk[tid+256] = k1;
    __syncthreads();
    int c0 = 0, c1 = 0;
    #pragma unroll 8
    for (int j = 0; j < 512; ++j) {
      unsigned long long kj = sk[j];
      c0 += (kj > k0); c1 += (kj > k1);
    }
    if (c0 == KTOP-1) skv[0] = v0;
    if (c1 == KTOP-1) skv[0] = v1;
    if (c0 == 0) skv[1] = v0;
    if (c1 == 0) skv[1] = v1;
    __syncthreads();
    float kth = skv[0], mx = skv[1];
    float e0 = (v0 >= kth) ? expf(v0-mx) : 0.f;
    float e1 = (v1 >= kth) ? expf(v1-mx) : 0.f;
    float s = wave_reduce(e0+e1);
    if (lane == 0) sred[wv] = s;
    __syncthreads();
    float inv = 1.f/(sred[0]+sred[1]+sred[2]+sred[3]);
    int brr = b*4 + r;
    cw[brr*Nn+tid]     = e0*inv;
    cw[brr*Nn+tid+256] = e1*inv;
  }
}

// ---- K2: fused w_r + psi + usage_new + rvec partial (block per (b, 256-chunk)) ----
__global__ void k_wrrv(const float* __restrict__ bwpart, const float* __restrict__ cw,
                       const float* __restrict__ fw, const float* __restrict__ rp,
                       const float* __restrict__ usage, const float* __restrict__ wwt,
                       const float* __restrict__ mem,
                       float* __restrict__ out_wr, float* __restrict__ out_usage,
                       float* __restrict__ rvec) {
  __shared__ float swr[4][256];
  int b = blockIdx.x >> 1, ch = blockIdx.x & 1;
  int tid = threadIdx.x;
  int n = ch*256 + tid;
  int idx = b*Nn + n;
  float psi = 1.f;
  #pragma unroll
  for (int r = 0; r < 4; ++r) {
    int brr = b*4 + r;
    float bwv = 0.f;
    #pragma unroll
    for (int chh = 0; chh < 8; ++chh)
      bwv += bwpart[((size_t)(chh*Bb + b)*Rr + r)*Nn + n];
    const float* rpb = rp + brr*4;
    float w = rpb[1]*bwv + rpb[2]*cw[brr*Nn+n] + rpb[3]*fw[brr*Nn+n];
    out_wr[brr*Nn+n] = w;
    swr[r][tid] = w;
    psi *= (1.f - w);
  }
  float u = usage[idx], wt = wwt[idx];
  out_usage[idx] = (u + wt - u*wt) * psi;
  __syncthreads();
  int r = tid >> 6, v = tid & 63;
  const float* mb = mem + ((size_t)b*Nn + ch*256)*Vv + v;
  float acc = 0.f;
  #pragma unroll 16
  for (int t = 0; t < 256; ++t) acc += swr[r][t] * mb[t*Vv];
  atomicAdd(&rvec[(b*4+r)*Vv + v], acc);
}

// ---- K3: gates GEMM fused with LSTM: wave computes 4 gates of one h x 4 b ----
__global__ void k_gates_lstm(const float* __restrict__ x, const float* __restrict__ rvec,
                             const float* __restrict__ h, const float* __restrict__ Wih,
                             const float* __restrict__ Whh, const float* __restrict__ bih,
                             const float* __restrict__ bhh, const float* __restrict__ c,
                             float* __restrict__ out_h, float* __restrict__ out_c) {
  int gid = blockIdx.x*4 + (threadIdx.x>>6);   // hh*16 + bt
  int lane = threadIdx.x & 63;
  int hh = gid >> 4;    // 0..511
  int bt = gid & 15;    // 0..15
  float acc[4][4] = {};
  #pragma unroll
  for (int t = 0; t < 6; ++t) {
    int k = lane + 64*t;
    float u[4], w[4];
    #pragma unroll
    for (int i = 0; i < 4; ++i) {
      int b = bt*4 + i;
      u[i] = (k < INp) ? x[b*INp + k] : rvec[b*(Rr*Vv) + k - INp];
      w[i] = Wih[(size_t)(i*Hh + hh)*CIN + k];     // i = gate index
    }
    #pragma unroll
    for (int g = 0; g < 4; ++g)
      #pragma unroll
      for (int bb = 0; bb < 4; ++bb) acc[g][bb] += w[g]*u[bb];
  }
  #pragma unroll
  for (int t = 0; t < 8; ++t) {
    int k = lane + 64*t;
    float u[4], w[4];
    #pragma unroll
    for (int i = 0; i < 4; ++i) {
      u[i] = h[(bt*4+i)*Hh + k];
      w[i] = Whh[(size_t)(i*Hh + hh)*Hh + k];
    }
    #pragma unroll
    for (int g = 0; g < 4; ++g)
      #pragma unroll
      for (int bb = 0; bb < 4; ++bb) acc[g][bb] += w[g]*u[bb];
  }
  #pragma unroll
  for (int g = 0; g < 4; ++g)
    #pragma unroll
    for (int bb = 0; bb < 4; ++bb) acc[g][bb] = wave_reduce(acc[g][bb]);
  if (lane == 0) {
    float bsum[4];
    #pragma unroll
    for (int g = 0; g < 4; ++g) bsum[g] = bih[g*Hh + hh] + bhh[g*Hh + hh];
    #pragma unroll
    for (int bb = 0; bb < 4; ++bb) {
      int b = bt*4 + bb;
      float ig = sigmoidf(acc[0][bb] + bsum[0]);
      float fg = sigmoidf(acc[1][bb] + bsum[1]);
      float gg = tanhf   (acc[2][bb] + bsum[2]);
      float og = sigmoidf(acc[3][bb] + bsum[3]);
      float cn = fg * c[b*Hh + hh] + ig * gg;
      float hn = og * tanhf(cn);
      out_c[b*Hh + hh] = cn;
      out_h[b*Hh + hh] = hn;
    }
  }
}

// ---- K4: wopol + wsim + alloc, block per b ----
__global__ void k_tail(const float* __restrict__ hn, const float* __restrict__ Ww,
                       const float* __restrict__ bw_, const float* __restrict__ Wp,
                       const float* __restrict__ bp, const float* __restrict__ Wv,
                       const float* __restrict__ bv, const float* __restrict__ usage,
                       const float* __restrict__ prec, const float* __restrict__ mem,
                       float* __restrict__ wo, float* __restrict__ out_logits,
                       float* __restrict__ out_value, float* __restrict__ out_ww,
                       float* __restrict__ out_prec) {
  __shared__ __align__(16) float sh[512];
  __shared__ __align__(16) float swo[200];
  __shared__ unsigned long long sk[512];
  __shared__ float su[512];
  __shared__ float cp[512];
  __shared__ float sred[8];
  int b = blockIdx.x, tid = threadIdx.x;
  int wv = tid >> 6, lane = tid & 63;
  const float* hb = hn + b*Hh;
  for (int i = tid; i < 512; i += 256) sh[i] = hb[i];
  __syncthreads();
  // phase A: 214 dots (195 wo + 18 logits + 1 value), 4-way interleave per wave
  int dbeg = wv*54, dend = (dbeg + 54 < 214) ? dbeg + 54 : 214;
  for (int p = dbeg; p < dend; p += 4) {
    int d1 = (p+1 < 213) ? p+1 : 213, d2 = (p+2 < 213) ? p+2 : 213, d3 = (p+3 < 213) ? p+3 : 213;
    const float* w0 = (p  < WOUT) ? Ww + (size_t)p *Hh : ((p  < WOUT+Aa) ? Wp + (size_t)(p -WOUT)*Hh : Wv);
    const float* w1 = (d1 < WOUT) ? Ww + (size_t)d1*Hh : ((d1 < WOUT+Aa) ? Wp + (size_t)(d1-WOUT)*Hh : Wv);
    const float* w2 = (d2 < WOUT) ? Ww + (size_t)d2*Hh : ((d2 < WOUT+Aa) ? Wp + (size_t)(d2-WOUT)*Hh : Wv);
    const float* w3 = (d3 < WOUT) ? Ww + (size_t)d3*Hh : ((d3 < WOUT+Aa) ? Wp + (size_t)(d3-WOUT)*Hh : Wv);
    float a0=0,a1=0,a2=0,a3=0;
    #pragma unroll
    for (int t = 0; t < 8; ++t) {
      int k = lane + 64*t; float hv = sh[k];
      a0 += w0[k]*hv; a1 += w1[k]*hv; a2 += w2[k]*hv; a3 += w3[k]*hv;
    }
    #pragma unroll
    for (int o = 32; o > 0; o >>= 1) {
      a0 += __shfl_down(a0,o,64); a1 += __shfl_down(a1,o,64);
      a2 += __shfl_down(a2,o,64); a3 += __shfl_down(a3,o,64);
    }
    if (lane == 0) {
      float av[4] = {a0,a1,a2,a3};
      #pragma unroll
      for (int i = 0; i < 4; ++i) {
        int d = p + i;
        if (d >= dend) break;
        float a = av[i];
        if (d < WOUT)          { float vv = a + bw_[d]; swo[d] = vv; wo[b*WOUT+d] = vv; }
        else if (d < WOUT+Aa)  { out_logits[b*Aa + (d-WOUT)] = a + bp[d-WOUT]; }
        else                   { out_value[b] = a + bv[0]; }
      }
    }
  }
  __syncthreads();
  // phase B: wsim, thread-per-row x2 (float4 dots; mem-norm + key-norm inline)
  float wbeta = softplusf(swo[192]);
  const float4* key4 = (const float4*)swo;
  float s0, s1;
  {
    const float4* m4 = (const float4*)(mem + ((size_t)(b*Nn + tid))*Vv);
    float dot=0.f, nrm=0.f, kn=0.f;
    #pragma unroll
    for (int i = 0; i < 16; ++i) {
      float4 mv = m4[i]; float4 kk = key4[i];
      dot += mv.x*kk.x + mv.y*kk.y + mv.z*kk.z + mv.w*kk.w;
      nrm += mv.x*mv.x + mv.y*mv.y + mv.z*mv.z + mv.w*mv.w;
      kn  += kk.x*kk.x + kk.y*kk.y + kk.z*kk.z + kk.w*kk.w;
    }
    s0 = wbeta * dot / (fmaxf(sqrtf(nrm), EPSf) * fmaxf(sqrtf(kn), EPSf));
  }
  {
    const float4* m4 = (const float4*)(mem + ((size_t)(b*Nn + tid + 256))*Vv);
    float dot=0.f, nrm=0.f, kn=0.f;
    #pragma unroll
    for (int i = 0; i < 16; ++i) {
      float4 mv = m4[i]; float4 kk = key4[i];
      dot += mv.x*kk.x + mv.y*kk.y + mv.z*kk.z + mv.w*kk.w;
      nrm += mv.x*mv.x + mv.y*mv.y + mv.z*mv.z + mv.w*mv.w;
      kn  += kk.x*kk.x + kk.y*kk.y + kk.z*kk.z + kk.w*kk.w;
    }
    s1 = wbeta * dot / (fmaxf(sqrtf(nrm), EPSf) * fmaxf(sqrtf(kn), EPSf));
  }
  // phase C: softmax(wsim) + rank-based allocation + write_w + prec_new
  float u0 = usage[b*Nn+tid], u1 = usage[b*Nn+tid+256];
  unsigned long long k0 = ((unsigned long long)f2ord(u0) << 32) | (unsigned)tid;
  unsigned long long k1 = ((unsigned long long)f2ord(u1) << 32) | (unsigned)(tid+256);
  sk[tid] = k0; sk[tid+256] = k1;
  float mxl = fmaxf(s0, s1);
  #pragma unroll
  for (int o = 32; o > 0; o >>= 1) mxl = fmaxf(mxl, __shfl_down(mxl,o,64));
  if (lane == 0) sred[wv] = mxl;
  __syncthreads();
  float mx = fmaxf(fmaxf(sred[0],sred[1]), fmaxf(sred[2],sred[3]));
  float e0 = expf(s0-mx), e1 = expf(s1-mx);
  float ssum = wave_reduce(e0+e1);
  if (lane == 0) sred[4+wv] = ssum;
  // rank loop overlaps the sum barrier
  int r0 = 0, r1 = 0;
  #pragma unroll 8
  for (int j = 0; j < 512; ++j) {
    unsigned long long kj = sk[j];
    r0 += (kj < k0); r1 += (kj < k1);
  }
  __syncthreads();
  float cinv = 1.f/(sred[4]+sred[5]+sred[6]+sred[7]);
  float c0 = e0*cinv, c1 = e1*cinv;
  su[r0] = u0; su[r1] = u1;       // scatter into sorted order (ranks are a permutation)
  __syncthreads();
  cp[tid] = su[tid]; cp[tid+256] = su[tid+256];
  __syncthreads();
  for (int d = 1; d < 512; d <<= 1) {
    float t0 = cp[tid]     * ((tid >= d)     ? cp[tid-d]     : 1.f);
    float t1 = cp[tid+256] * ((tid+256 >= d) ? cp[tid+256-d] : 1.f);
    __syncthreads();
    cp[tid] = t0; cp[tid+256] = t1;
    __syncthreads();
  }
  float pp0 = (r0 == 0) ? 1.f : cp[r0-1];
  float pp1 = (r1 == 0) ? 1.f : cp[r1-1];
  float a0 = (1.f-u0)*pp0, a1 = (1.f-u1)*pp1;
  float ga = sigmoidf(swo[193]);
  float gw = sigmoidf(swo[194]);
  float wv0 = gw * (ga*a0 + (1.f-ga)*c0);
  float wv1 = gw * (ga*a1 + (1.f-ga)*c1);
  out_ww[b*Nn+tid]     = wv0;
  out_ww[b*Nn+tid+256] = wv1;
  float ws_ = wave_reduce(wv0+wv1);
  if (lane == 0) sred[wv] = ws_;
  __syncthreads();
  float wsum = sred[0]+sred[1]+sred[2]+sred[3];
  out_prec[b*Nn+tid]     = (1.f-wsum)*prec[b*Nn+tid]     + wv0;
  out_prec[b*Nn+tid+256] = (1.f-wsum)*prec[b*Nn+tid+256] + wv1;
}

// ---- K5: fused link_new + mem_new elementwise, float4 ----
__global__ void k_memlink(const float* __restrict__ link, const float* __restrict__ ww,
                          const float* __restrict__ prec, const float* __restrict__ mem,
                          const float* __restrict__ wo, float* __restrict__ out_link,
                          float* __restrict__ out_mem) {
  int bid = blockIdx.x;
  if (bid < 16384) {
    int idx4 = bid*256 + threadIdx.x;
    int base = idx4*4;
    int b = base >> 18;
    int rem = base & 262143;
    int i = rem >> 9;
    int j0 = rem & 511;
    float wi = ww[b*Nn + i];
    float fi = 1.f - wi;
    float4 lv = *(const float4*)(link + base);
    float4 wj = *(const float4*)(ww + b*Nn + j0);
    float4 pj = *(const float4*)(prec + b*Nn + j0);
    float4 o;
    o.x = fi*(1.f-wj.x)*lv.x + wi*pj.x;
    o.y = fi*(1.f-wj.y)*lv.y + wi*pj.y;
    o.z = fi*(1.f-wj.z)*lv.z + wi*pj.z;
    o.w = fi*(1.f-wj.w)*lv.w + wi*pj.w;
    if (i >= j0 && i < j0+4) {
      if (i == j0) o.x = 0.f;
      else if (i == j0+1) o.y = 0.f;
      else if (i == j0+2) o.z = 0.f;
      else o.w = 0.f;
    }
    *(float4*)(out_link + base) = o;
  } else {
    int idx4 = (bid - 16384)*256 + threadIdx.x;
    int base = idx4*4;
    int b = base >> 15;
    int rem = base & 32767;
    int n = rem >> 6;
    int v0 = rem & 63;
    float w = ww[b*Nn + n];
    const float* wob = wo + b*WOUT;
    float4 m = *(const float4*)(mem + base);
    float4 o;
    float e, a;
    e = sigmoidf(wob[64+v0+0]); a = tanhf(wob[128+v0+0]); o.x = m.x*(1.f-w*e)+w*a;
    e = sigmoidf(wob[64+v0+1]); a = tanhf(wob[128+v0+1]); o.y = m.y*(1.f-w*e)+w*a;
    e = sigmoidf(wob[64+v0+2]); a = tanhf(wob[128+v0+2]); o.z = m.z*(1.f-w*e)+w*a;
    e = sigmoidf(wob[64+v0+3]); a = tanhf(wob[128+v0+3]); o.w = m.w*(1.f-w*e)+w*a;
    *(float4*)(out_mem + base) = o;
  }
}

extern "C" void kernel_launch(void* const* d_in, const int* in_sizes, int n_in,
                              void* d_out, int out_size, void* d_ws, size_t ws_size,
                              hipStream_t stream) {
  const float* x    = (const float*)d_in[0];
  const float* h    = (const float*)d_in[1];
  const float* c    = (const float*)d_in[2];
  const float* mem  = (const float*)d_in[3];
  const float* rw   = (const float*)d_in[4];
  const float* wwt  = (const float*)d_in[5];
  const float* usage= (const float*)d_in[6];
  const float* link = (const float*)d_in[7];
  const float* prec = (const float*)d_in[8];
  const float* Wih  = (const float*)d_in[9];
  const float* Whh  = (const float*)d_in[10];
  const float* bih  = (const float*)d_in[11];
  const float* bhh  = (const float*)d_in[12];
  const float* Wr   = (const float*)d_in[13];
  const float* br   = (const float*)d_in[14];
  const float* Ww   = (const float*)d_in[15];
  const float* bw_  = (const float*)d_in[16];
  const float* Wp   = (const float*)d_in[17];
  const float* bp   = (const float*)d_in[18];
  const float* Wv   = (const float*)d_in[19];
  const float* bv   = (const float*)d_in[20];

  float* out = (float*)d_out;
  float* o_logits = out + 0;
  float* o_value  = out + 1152;
  float* o_h      = out + 1216;
  float* o_c      = out + 33984;
  float* o_mem    = out + 66752;
  float* o_wr     = out + 2163904;
  float* o_ww     = out + 2294976;
  float* o_usage  = out + 2327744;
  float* o_link   = out + 2360512;
  float* o_prec   = out + 19137728;

  float* ws = (float*)d_ws;
  float* ws_rp     = ws;              // 1024  (b,r): {rbeta/knorm, pi0, pi1, pi2}
  float* ws_cw     = ws + 1024;       // 131072
  float* ws_fw     = ws + 132096;     // 131072
  float* ws_bwpart = ws + 263168;     // 1048576
  float* ws_rvec   = ws + 1311744;    // 16384 (zeroed in k_stage1, atomic acc in K2)
  float* ws_wo     = ws + 1328128;    // 12480  (end ~5.4 MB)

  k_stage1     <<<dim3(768),        dim3(256), 0, stream>>>(link, rw, Wr, br, h, mem, ws_fw, ws_bwpart, ws_rvec, ws_rp, ws_cw);
  k_wrrv       <<<dim3(Bb*2),       dim3(256), 0, stream>>>(ws_bwpart, ws_cw, ws_fw, ws_rp, usage, wwt, mem, o_wr, o_usage, ws_rvec);
  k_gates_lstm <<<dim3(2048),       dim3(256), 0, stream>>>(x, ws_rvec, h, Wih, Whh, bih, bhh, c, o_h, o_c);
  k_tail       <<<dim3(Bb),         dim3(256), 0, stream>>>(o_h, Ww, bw_, Wp, bp, Wv, bv, usage, prec, mem, ws_wo, o_logits, o_value, o_ww, o_prec);
  k_memlink    <<<dim3(16384+2048), dim3(256), 0, stream>>>(link, o_ww, prec, mem, ws_wo, o_link, o_mem);
}